// Round 4
// baseline (131.759 us; speedup 1.0000x reference)
//
#include <hip/hip_runtime.h>
#include <math.h>

// RNTN over a complete binary tree, E=32 (EE=1024 floats per state matrix).
// Key structure: every internal node is consumed by exactly ONE parent, so a
// block computing a depth-3 subtree (7 nodes) keeps all intermediate states
// in LDS and writes only the subtree root. 11 levels + head = 3 launches:
//   A: 256 blocks, levels 1-3 (children = relu(emb[leaf words]))
//   B:  32 blocks, levels 4-6 (children = A's outputs)
//   tail: 1 block x 1024 thr, levels 7-11 (16+8+4+2+1) + projection head.
// d_ws: states for internal nodes, states[(node - L) * 1024].

#define EE 1024

__device__ __forceinline__ float4 relu4(float4 v) {
    v.x = fmaxf(v.x, 0.f); v.y = fmaxf(v.y, 0.f);
    v.z = fmaxf(v.z, 0.f); v.w = fmaxf(v.w, 0.f);
    return v;
}

// Compute k nodes (k in {1,2,4}) with 256 threads.
// cbuf: children, node m's children at cbuf[2m], cbuf[2m+1] (EE floats each).
// obuf[m*EE + e] = relu(Lchild @ (W @ Rchild) + bias). obuf may be LDS or global.
__device__ __forceinline__ void level_compute(
    int k, int t, const float* __restrict__ sW, const float* __restrict__ cbuf,
    float* __restrict__ sT, float* __restrict__ obuf, const float* __restrict__ bias)
{
    for (int p = 0; p < 4 * k; ++p) {
        const int o = t + p * 256, m = o >> 10, e = o & 1023, r = e >> 5, c = e & 31;
        float acc = 0.f;
        #pragma unroll
        for (int kk = 0; kk < 32; ++kk)
            acc = fmaf(sW[m * EE + r * 32 + kk], cbuf[(2 * m + 1) * EE + kk * 32 + c], acc);
        sT[o] = acc;
    }
    __syncthreads();
    for (int p = 0; p < 4 * k; ++p) {
        const int o = t + p * 256, m = o >> 10, e = o & 1023, r = e >> 5, c = e & 31;
        float acc = bias[e];
        #pragma unroll
        for (int kk = 0; kk < 32; ++kk)
            acc = fmaf(cbuf[2 * m * EE + r * 32 + kk], sT[m * EE + kk * 32 + c], acc);
        obuf[m * EE + e] = fmaxf(acc, 0.f);
    }
    __syncthreads();
}

// One block per depth-3 subtree root (root at rootBase + blockIdx.x).
// LEAF: the subtree's children are leaves -> state = relu(emb[words[leaf]]).
template<bool LEAF>
__global__ __launch_bounds__(256) void subtree3_kernel(
    const int* __restrict__ words, const int* __restrict__ left,
    const int* __restrict__ right, const float* __restrict__ emb,
    const float* __restrict__ bias, float* __restrict__ states,
    int rootBase, int Lleaves)
{
    __shared__ float sA[8 * EE];   // 32 KB: child states / level outputs
    __shared__ float sB[4 * EE];   // 16 KB
    __shared__ float sW[4 * EE];   // 16 KB
    __shared__ float sT[4 * EE];   // 16 KB
    const int t = threadIdx.x;
    const int root = rootBase + blockIdx.x;

    int c1[2], c2[4], c3[8];
    c1[0] = left[root]; c1[1] = right[root];
    #pragma unroll
    for (int j = 0; j < 2; ++j) { c2[2 * j] = left[c1[j]]; c2[2 * j + 1] = right[c1[j]]; }
    #pragma unroll
    for (int j = 0; j < 4; ++j) { c3[2 * j] = left[c2[j]]; c3[2 * j + 1] = right[c2[j]]; }

    // stage 8 bottom children into sA (one float4 per thread per state)
    #pragma unroll
    for (int s = 0; s < 8; ++s) {
        const float* src = LEAF ? (emb + (size_t)words[c3[s]] * EE)
                                : (states + (size_t)(c3[s] - Lleaves) * EE);
        float4 v = reinterpret_cast<const float4*>(src)[t];
        if (LEAF) v = relu4(v);
        reinterpret_cast<float4*>(sA + s * EE)[t] = v;
    }
    #pragma unroll
    for (int s = 0; s < 4; ++s)
        reinterpret_cast<float4*>(sW + s * EE)[t] =
            reinterpret_cast<const float4*>(emb + (size_t)words[c2[s]] * EE)[t];
    __syncthreads();
    level_compute(4, t, sW, sA, sT, sB, bias);            // c2 outputs -> sB

    #pragma unroll
    for (int s = 0; s < 2; ++s)
        reinterpret_cast<float4*>(sW + s * EE)[t] =
            reinterpret_cast<const float4*>(emb + (size_t)words[c1[s]] * EE)[t];
    __syncthreads();
    level_compute(2, t, sW, sB, sT, sA, bias);            // c1 outputs -> sA

    reinterpret_cast<float4*>(sW)[t] =
        reinterpret_cast<const float4*>(emb + (size_t)words[root] * EE)[t];
    __syncthreads();
    level_compute(1, t, sW, sA, sT,
                  states + (size_t)(root - Lleaves) * EE, bias);  // root -> global
}

// Single block: levels of 16, 8, 4, 2, 1 nodes + projection head.
// Each level processed in groups of <=4 nodes, fully LDS-staged.
__global__ __launch_bounds__(1024) void tail_kernel(
    const int* __restrict__ words, const int* __restrict__ left,
    const int* __restrict__ right, const float* __restrict__ emb,
    const float* __restrict__ bias, float* __restrict__ states,
    const float* __restrict__ W_proj, const float* __restrict__ b_proj,
    const int* __restrict__ label, float* __restrict__ out,
    int base0, int cnt0, int Lleaves)
{
    __shared__ float sC[8 * EE];   // 32 KB: children of current group
    __shared__ float sW[4 * EE];   // 16 KB
    __shared__ float sT[4 * EE];   // 16 KB
    __shared__ float sLog[128];
    const int t = threadIdx.x;
    const int r = t >> 5, c = t & 31;

    int base = base0;
    for (int cnt = cnt0; cnt >= 1; cnt >>= 1) {
        for (int g0 = 0; g0 < cnt; g0 += 4) {
            const int g = (cnt - g0 < 4) ? (cnt - g0) : 4;
            // stage 2g children + g W matrices (3g states) as float4
            for (int q = t; q < 3 * g * 256; q += 1024) {
                const int s = q >> 8, idx4 = q & 255;
                const float* src; float* dst;
                if (s < 2 * g) {
                    const int node = base + g0 + (s >> 1);
                    const int ch = (s & 1) ? right[node] : left[node];
                    src = states + (size_t)(ch - Lleaves) * EE;
                    dst = sC + s * EE;
                } else {
                    const int m = s - 2 * g;
                    src = emb + (size_t)words[base + g0 + m] * EE;
                    dst = sW + m * EE;
                }
                reinterpret_cast<float4*>(dst)[idx4] =
                    reinterpret_cast<const float4*>(src)[idx4];
            }
            __syncthreads();
            for (int m = 0; m < g; ++m) {                 // T = W @ Rchild
                float acc = 0.f;
                #pragma unroll
                for (int kk = 0; kk < 32; ++kk)
                    acc = fmaf(sW[m * EE + r * 32 + kk], sC[(2 * m + 1) * EE + kk * 32 + c], acc);
                sT[m * EE + t] = acc;
            }
            __syncthreads();
            for (int m = 0; m < g; ++m) {                 // S = relu(L @ T + bias)
                float acc = bias[t];
                #pragma unroll
                for (int kk = 0; kk < 32; ++kk)
                    acc = fmaf(sC[2 * m * EE + r * 32 + kk], sT[m * EE + kk * 32 + c], acc);
                states[(size_t)(base + g0 + m - Lleaves) * EE + t] = fmaxf(acc, 0.f);
            }
            __syncthreads();
        }
        base += cnt;
    }

    // Head: logits = root @ W_proj^T + b_proj ; loss = -log_softmax[label]
    const float* root = states + (size_t)(base - 1 - Lleaves) * EE;
    {
        const int j = t >> 3, part = t & 7;   // 8 threads per logit
        const float* Wr = W_proj + (size_t)j * EE + part * 128;
        const float* rt = root + part * 128;
        float acc = 0.f;
        #pragma unroll
        for (int k = 0; k < 128; k += 4) {
            const float4 w4 = *reinterpret_cast<const float4*>(Wr + k);
            const float4 r4 = *reinterpret_cast<const float4*>(rt + k);
            acc = fmaf(w4.x, r4.x, acc);
            acc = fmaf(w4.y, r4.y, acc);
            acc = fmaf(w4.z, r4.z, acc);
            acc = fmaf(w4.w, r4.w, acc);
        }
        acc += __shfl_xor(acc, 1);
        acc += __shfl_xor(acc, 2);
        acc += __shfl_xor(acc, 4);
        if (part == 0) sLog[j] = acc + b_proj[j];
    }
    __syncthreads();

    if (t < 64) {  // wave 0: max/argmax (first-index tie-break), logsumexp
        const float v0 = sLog[t], v1 = sLog[t + 64];
        float m; int mi;
        if (v1 > v0) { m = v1; mi = t + 64; } else { m = v0; mi = t; }
        #pragma unroll
        for (int d = 1; d < 64; d <<= 1) {
            const float om = __shfl_xor(m, d);
            const int omi = __shfl_xor(mi, d);
            if (om > m || (om == m && omi < mi)) { m = om; mi = omi; }
        }
        float se = expf(v0 - m) + expf(v1 - m);
        #pragma unroll
        for (int d = 1; d < 64; d <<= 1) se += __shfl_xor(se, d);
        if (t == 0) {
            out[0] = (float)mi;                              // prediction
            out[1] = -(sLog[label[0]] - m - logf(se));       // loss
        }
    }
}

extern "C" void kernel_launch(void* const* d_in, const int* in_sizes, int n_in,
                              void* d_out, int out_size, void* d_ws, size_t ws_size,
                              hipStream_t stream) {
    (void)n_in; (void)out_size; (void)ws_size;
    const int*   words  = (const int*)  d_in[0];
    const int*   left   = (const int*)  d_in[1];
    const int*   right  = (const int*)  d_in[2];
    // d_in[3] = is_leaf (unused: leaves are exactly nodes [0, L))
    const float* emb    = (const float*)d_in[4];
    const float* bias   = (const float*)d_in[5];
    const float* W_proj = (const float*)d_in[6];
    const float* b_proj = (const float*)d_in[7];
    const int*   label  = (const int*)  d_in[8];
    float* out    = (float*)d_out;
    float* states = (float*)d_ws;   // (N - L) * 1024 floats = 8.4 MB

    const int N = in_sizes[0];      // 4095
    const int L = (N + 1) / 2;      // 2048

    const int base3 = L + L / 2 + L / 4;                  // 3584: first level-3 node
    subtree3_kernel<true><<<L / 8, 256, 0, stream>>>(
        words, left, right, emb, bias, states, base3, L);

    const int base6 = base3 + L / 8 + L / 16 + L / 32;    // 4032: first level-6 node
    subtree3_kernel<false><<<L / 64, 256, 0, stream>>>(
        words, left, right, emb, bias, states, base6, L);

    const int baseT = base6 + L / 64;                     // 4064: first level-7 node
    tail_kernel<<<1, 1024, 0, stream>>>(
        words, left, right, emb, bias, states, W_proj, b_proj, label, out,
        baseT, L / 128, L);
}